// Round 6
// baseline (64.405 us; speedup 1.0000x reference)
//
#include <hip/hip_runtime.h>
#include <cstdint>
#include <cstddef>

// Problem constants
#define B_ 256
#define D_ 512
#define P_ 128
#define E_ 128

typedef unsigned short u16;
typedef unsigned int   u32;
typedef __bf16  bf16x8_t __attribute__((ext_vector_type(8)));
typedef float   f32x4_t  __attribute__((ext_vector_type(4)));
typedef u16     u16x8_t  __attribute__((ext_vector_type(8)));

__device__ __forceinline__ u16 f2bf(float f) {
  union { float f; unsigned int u; } c; c.f = f;
  unsigned int u = c.u;
  unsigned int r = (u + 0x7FFFu + ((u >> 16) & 1u)) >> 16;
  return (u16)r;
}

// ---------------------------------------------------------------------------
// Pass 1: transpose + convert f32 -> bf16 (verified, parametrized).
// src viewed as [outer][R=512][C=128] f32; dst elem (o,r,c) at
// c*dst_row_stride + o*dst_outer_stride + r.
//   x: outer=b, c=p -> xT[p][b][d]: row_stride=B_*D_, outer_stride=D_
//   W: outer=p, c=e -> Wt[p][e][d]: row_stride=D_,    outer_stride=E_*D_
// ---------------------------------------------------------------------------
__global__ __launch_bounds__(256) void transpose_cvt_kernel(
    const float* __restrict__ src, u16* __restrict__ dst,
    size_t dst_row_stride, size_t dst_outer_stride) {
  __shared__ float tile[64][65];

  const int o  = blockIdx.x;
  const int r0 = blockIdx.y * 64;
  const int c0 = blockIdx.z * 64;
  const int t  = threadIdx.x;

  const float* s = src + (size_t)o * D_ * 128 + (size_t)r0 * 128 + c0;

  {
    const int lr = t >> 4;
    const int lc = (t & 15) * 4;
    #pragma unroll
    for (int it = 0; it < 4; ++it) {
      const int r = lr + it * 16;
      const float4 v = *reinterpret_cast<const float4*>(s + (size_t)r * 128 + lc);
      tile[r][lc + 0] = v.x; tile[r][lc + 1] = v.y;
      tile[r][lc + 2] = v.z; tile[r][lc + 3] = v.w;
    }
  }
  __syncthreads();

  {
    const int wc = t >> 3;
    const int wd = (t & 7) * 8;
    #pragma unroll
    for (int it = 0; it < 2; ++it) {
      const int c = wc + it * 32;
      u16x8_t pkv;
      #pragma unroll
      for (int j = 0; j < 8; ++j) pkv[j] = f2bf(tile[wd + j][c]);
      *reinterpret_cast<u16x8_t*>(dst + (size_t)(c0 + c) * dst_row_stride +
                                  (size_t)o * dst_outer_stride + r0 + wd) = pkv;
    }
  }
}

// ---------------------------------------------------------------------------
// Pass 2: per-p GEMM with a BARRIER-FREE K-loop.
// WG = one p x 32 b-rows x all 128 e. A-slab (32x512 bf16 = 32KB) staged to
// LDS once (pre-swizzled global source, linear LDS dest, rule #21), ONE
// vmcnt(0)+barrier, then a fully-unrolled K-loop with no synchronization:
//   wave wv owns e in [32wv, 32wv+32); per kk: 2 ds_read_b128 (A, swizzled,
//   conflict-free) + 2 global 16B loads (B rows, immediate offsets) + 4 MFMA.
// Latency hidden by ILP (unrolled, many loads in flight) + TLP (16 waves/CU),
// not by lockstep barriers — kills the 8-iter barrier-paced serialization
// that held rounds 2-5 at ~100 TF.
// Grid = 128p x 8bt = 1024 WGs = 4 WG/CU; XCD swizzle: p in [16*xcd,16*xcd+16)
// -> Wt slice (2MB) L2-resident per XCD, out-lines merge in that L2.
// ---------------------------------------------------------------------------

// involutive chunk swizzle: logical 16B chunk c (0..63) of row (0..31) lives
// at chunk index (c&56)|((c^row)&7); elem index:
#define SWZA(row, c) ((size_t)(row) * 512 + ((((c) & 56) | (((c) ^ (row)) & 7)) << 3))

__global__ __launch_bounds__(256, 4) void gemm_kernel(
    const u16* __restrict__ xT, const u16* __restrict__ Wt,
    const float* __restrict__ bias, float* __restrict__ out) {
  __shared__ __attribute__((aligned(16))) u16 As[32 * 512];   // 32 KB

  const int wg  = blockIdx.x;
  const int xcd = wg & 7;
  const int i   = wg >> 3;             // 0..127
  const int p   = xcd * 16 + (i & 15);
  const int b0  = (i >> 4) * 32;       // 0,32,..,224

  const int t    = threadIdx.x;
  const int lane = t & 63;
  const int wv   = t >> 6;             // wave 0..3 -> e block
  const int fr   = lane & 15;
  const int fq   = lane >> 4;

  const u16* Ag = xT + (size_t)p * (B_ * D_) + (size_t)b0 * D_;

  // ---- stage A-slab: 2048 chunks of 16B; thread t stages chunks t+256j ----
  #pragma unroll
  for (int j = 0; j < 8; ++j) {
    const int cid = t + 256 * j;
    const int row = cid >> 6;          // 0..31
    const int g   = cid & 63;
    __builtin_amdgcn_global_load_lds(
        (const __attribute__((address_space(1))) void*)
            (Ag + (size_t)row * D_ + (((g & 56) | ((g ^ row) & 7)) << 3)),
        (__attribute__((address_space(3))) void*)&As[(size_t)wv * 512 + (size_t)j * 2048],
        16, 0, 0);
  }
  asm volatile("s_waitcnt vmcnt(0)" ::: "memory");
  __builtin_amdgcn_sched_barrier(0);
  __builtin_amdgcn_s_barrier();

  // ---- barrier-free K loop ----
  const u16* B0p = Wt + ((size_t)p * E_ + wv * 32 + fr) * D_ + fq * 8;
  const u16* B1p = B0p + (size_t)16 * D_;

  f32x4_t acc00 = {}, acc01 = {}, acc10 = {}, acc11 = {};

#define MFMA(a, b, c) __builtin_amdgcn_mfma_f32_16x16x32_bf16((a), (b), (c), 0, 0, 0)
  #pragma unroll
  for (int kk = 0; kk < 16; ++kk) {
    const int c = kk * 4 + fq;
    bf16x8_t a0 = *reinterpret_cast<const bf16x8_t*>(&As[SWZA(fr, c)]);
    bf16x8_t a1 = *reinterpret_cast<const bf16x8_t*>(&As[SWZA(fr + 16, c)]);
    bf16x8_t b0 = *reinterpret_cast<const bf16x8_t*>(B0p + kk * 32);
    bf16x8_t b1 = *reinterpret_cast<const bf16x8_t*>(B1p + kk * 32);
    acc00 = MFMA(a0, b0, acc00);
    acc01 = MFMA(a0, b1, acc01);
    acc10 = MFMA(a1, b0, acc10);
    acc11 = MFMA(a1, b1, acc11);
  }
#undef MFMA

  // ---- epilogue: C/D col=lane&15 (e), row=fq*4+rg (b) ----
  const int q4 = fq * 4;
  #pragma unroll
  for (int jj = 0; jj < 2; ++jj) {
    const int e  = wv * 32 + jj * 16 + fr;
    const float bv = bias[p * E_ + e];
    const f32x4_t v0 = (jj == 0) ? acc00 : acc01;   // ii=0
    const f32x4_t v1 = (jj == 0) ? acc10 : acc11;   // ii=1
    #pragma unroll
    for (int rg = 0; rg < 4; ++rg) {
      out[((size_t)(b0 + 0  + q4 + rg) * E_ + e) * P_ + p] = v0[rg] + bv;
      out[((size_t)(b0 + 16 + q4 + rg) * E_ + e) * P_ + p] = v1[rg] + bv;
    }
  }
}

// ---------------------------------------------------------------------------
// Fallback (only if workspace is too small): naive but correct.
// ---------------------------------------------------------------------------
__global__ __launch_bounds__(256) void naive_kernel(
    const float* __restrict__ x, const float* __restrict__ W,
    const float* __restrict__ bias, float* __restrict__ out) {
  const size_t idx = (size_t)blockIdx.x * 256 + threadIdx.x;
  const int p = (int)(idx & 127);
  const int e = (int)((idx >> 7) & 127);
  const int b = (int)(idx >> 14);
  float acc = bias[p * E_ + e];
  const float* xp = x + (size_t)b * D_ * P_ + p;
  const float* wp = W + (size_t)p * D_ * E_ + e;
  for (int d = 0; d < D_; ++d) acc += xp[(size_t)d * P_] * wp[(size_t)d * E_];
  out[idx] = acc;
}

extern "C" void kernel_launch(void* const* d_in, const int* in_sizes, int n_in,
                              void* d_out, int out_size, void* d_ws, size_t ws_size,
                              hipStream_t stream) {
  (void)in_sizes; (void)n_in; (void)out_size;
  const float* x    = (const float*)d_in[0];   // [B,D,P] f32
  const float* W    = (const float*)d_in[1];   // [P,D,E] f32
  const float* bias = (const float*)d_in[2];   // [P,E]   f32
  float* out = (float*)d_out;                  // [B,E,P] f32

  const size_t xT_bytes = (size_t)P_ * B_ * D_ * 2;   // 32 MiB
  const size_t Wt_bytes = (size_t)P_ * E_ * D_ * 2;   // 16 MiB

  if (ws_size < xT_bytes + Wt_bytes) {
    naive_kernel<<<dim3((B_ * E_ * P_) / 256), 256, 0, stream>>>(x, W, bias, out);
    return;
  }

  u16* xT = (u16*)d_ws;                                 // [P][B][D] bf16
  u16* Wt = (u16*)((char*)d_ws + xT_bytes);             // [P][E][D] bf16

  transpose_cvt_kernel<<<dim3(B_, 8, 2), 256, 0, stream>>>(
      x, xT, (size_t)B_ * D_, (size_t)D_);
  transpose_cvt_kernel<<<dim3(P_, 8, 2), 256, 0, stream>>>(
      W, Wt, (size_t)D_, (size_t)E_ * D_);

  gemm_kernel<<<dim3(1024), 256, 0, stream>>>(xT, Wt, bias, out);
}

// Round 7
// 46.852 us; speedup vs baseline: 1.3747x; 1.3747x over previous
//
#include <hip/hip_runtime.h>
#include <cstdint>
#include <cstddef>

// Problem constants
#define B_ 256
#define D_ 512
#define P_ 128
#define E_ 128

typedef unsigned short u16;
typedef unsigned int   u32;
typedef __bf16  bf16x8_t __attribute__((ext_vector_type(8)));
typedef float   f32x4_t  __attribute__((ext_vector_type(4)));
typedef u16     u16x8_t  __attribute__((ext_vector_type(8)));

__device__ __forceinline__ u16 f2bf(float f) {
  union { float f; unsigned int u; } c; c.f = f;
  unsigned int u = c.u;
  unsigned int r = (u + 0x7FFFu + ((u >> 16) & 1u)) >> 16;
  return (u16)r;
}

// ---------------------------------------------------------------------------
// Pass 1: transpose + convert f32 -> bf16 (verified, parametrized).
// src viewed as [outer][R=512][C=128] f32; dst elem (o,r,c) at
// c*dst_row_stride + o*dst_outer_stride + r.
//   x: outer=b, c=p -> xT[p][b][d]: row_stride=B_*D_, outer_stride=D_
//   W: outer=p, c=e -> Wt[p][e][d]: row_stride=D_,    outer_stride=E_*D_
// ---------------------------------------------------------------------------
__global__ __launch_bounds__(256) void transpose_cvt_kernel(
    const float* __restrict__ src, u16* __restrict__ dst,
    size_t dst_row_stride, size_t dst_outer_stride) {
  __shared__ float tile[64][65];

  const int o  = blockIdx.x;
  const int r0 = blockIdx.y * 64;
  const int c0 = blockIdx.z * 64;
  const int t  = threadIdx.x;

  const float* s = src + (size_t)o * D_ * 128 + (size_t)r0 * 128 + c0;

  {
    const int lr = t >> 4;
    const int lc = (t & 15) * 4;
    #pragma unroll
    for (int it = 0; it < 4; ++it) {
      const int r = lr + it * 16;
      const float4 v = *reinterpret_cast<const float4*>(s + (size_t)r * 128 + lc);
      tile[r][lc + 0] = v.x; tile[r][lc + 1] = v.y;
      tile[r][lc + 2] = v.z; tile[r][lc + 3] = v.w;
    }
  }
  __syncthreads();

  {
    const int wc = t >> 3;
    const int wd = (t & 7) * 8;
    #pragma unroll
    for (int it = 0; it < 2; ++it) {
      const int c = wc + it * 32;
      u16x8_t pkv;
      #pragma unroll
      for (int j = 0; j < 8; ++j) pkv[j] = f2bf(tile[wd + j][c]);
      *reinterpret_cast<u16x8_t*>(dst + (size_t)(c0 + c) * dst_row_stride +
                                  (size_t)o * dst_outer_stride + r0 + wd) = pkv;
    }
  }
}

// ---------------------------------------------------------------------------
// Pass 2: per-p bf16 TN GEMM (round-5 structure: all-bf16 global_load_lds
// staging, depth-2 counted-vmcnt pipeline, 64x64xBK64, 4 waves, 4 WG/CU).
// CHANGED epilogue: stores COALESCED to ws2[p][b][e] (16 lanes = one 64B
// line) instead of 4B-scattered out[b][e][p] — kills the ~4M single-dword
// L2 write transactions that held rounds 1-6 at a ~30-45us floor.
// ---------------------------------------------------------------------------

// swizzled elem index of 16B chunk g (0..7) in row `row` of a [64]x[64]-u16 tile
#define SWZ_ELEM(row, g) (((row) << 6) + ((((g) ^ ((row) & 7))) << 3))

__global__ __launch_bounds__(256, 4) void gemm_kernel(
    const u16* __restrict__ xT, const u16* __restrict__ Wt,
    const float* __restrict__ bias, float* __restrict__ ws2) {
  __shared__ __attribute__((aligned(16))) u16 As[2][64 * 64];
  __shared__ __attribute__((aligned(16))) u16 Bs[2][64 * 64];

  const int wg   = blockIdx.x;
  const int xcd  = wg & 7;
  const int i    = wg >> 3;            // 0..127
  const int p    = xcd * 16 + (i & 15);
  const int tile = i >> 4;             // 0..7
  const int b0   = (tile & 3) * 64;
  const int e0t  = (tile >> 2) * 64;

  const int t    = threadIdx.x;
  const int lane = t & 63;
  const int wv   = t >> 6;
  const int wr   = wv >> 1;            // wave row (b half)
  const int wc   = wv & 1;             // wave col (e half)

  const u16* Ag = xT + (size_t)p * (B_ * D_) + (size_t)b0 * D_;
  const u16* Bg = Wt + ((size_t)p * E_ + e0t) * D_;

  // staging: thread t stages 16B chunks t and t+256; LDS dest linear,
  // global source chunk pre-XOR-swizzled within its 128B row.
  const int r1 = t >> 3;
  const int sw = (((t & 7) ^ (r1 & 7)) << 3);

  const int fr = lane & 15;
  const int fq = lane >> 4;

  f32x4_t acc[2][2] = {};

#define STAGE_AB(buf, d0) do { \
    __builtin_amdgcn_global_load_lds( \
        (const __attribute__((address_space(1))) void*)(Ag + (size_t)r1 * D_ + (d0) + sw), \
        (__attribute__((address_space(3))) void*)&As[buf][wv * 512], 16, 0, 0); \
    __builtin_amdgcn_global_load_lds( \
        (const __attribute__((address_space(1))) void*)(Ag + (size_t)(r1 + 32) * D_ + (d0) + sw), \
        (__attribute__((address_space(3))) void*)&As[buf][2048 + wv * 512], 16, 0, 0); \
    __builtin_amdgcn_global_load_lds( \
        (const __attribute__((address_space(1))) void*)(Bg + (size_t)r1 * D_ + (d0) + sw), \
        (__attribute__((address_space(3))) void*)&Bs[buf][wv * 512], 16, 0, 0); \
    __builtin_amdgcn_global_load_lds( \
        (const __attribute__((address_space(1))) void*)(Bg + (size_t)(r1 + 32) * D_ + (d0) + sw), \
        (__attribute__((address_space(3))) void*)&Bs[buf][2048 + wv * 512], 16, 0, 0); \
  } while (0)

#define MFMA(a, b, c) __builtin_amdgcn_mfma_f32_16x16x32_bf16((a), (b), (c), 0, 0, 0)

#define K_ITER(KT, PREFETCH, VMSTR, LAST) do { \
    const int rowa = wr * 32 + fr, rowb = wc * 32 + fr; \
    bf16x8_t af0 = *reinterpret_cast<const bf16x8_t*>(&As[(KT) & 1][SWZ_ELEM(rowa, fq)]); \
    bf16x8_t af1 = *reinterpret_cast<const bf16x8_t*>(&As[(KT) & 1][SWZ_ELEM(rowa, 4 + fq)]); \
    bf16x8_t af2 = *reinterpret_cast<const bf16x8_t*>(&As[(KT) & 1][SWZ_ELEM(rowa + 16, fq)]); \
    bf16x8_t af3 = *reinterpret_cast<const bf16x8_t*>(&As[(KT) & 1][SWZ_ELEM(rowa + 16, 4 + fq)]); \
    bf16x8_t bf0 = *reinterpret_cast<const bf16x8_t*>(&Bs[(KT) & 1][SWZ_ELEM(rowb, fq)]); \
    bf16x8_t bf1 = *reinterpret_cast<const bf16x8_t*>(&Bs[(KT) & 1][SWZ_ELEM(rowb, 4 + fq)]); \
    bf16x8_t bf2 = *reinterpret_cast<const bf16x8_t*>(&Bs[(KT) & 1][SWZ_ELEM(rowb + 16, fq)]); \
    bf16x8_t bf3 = *reinterpret_cast<const bf16x8_t*>(&Bs[(KT) & 1][SWZ_ELEM(rowb + 16, 4 + fq)]); \
    asm volatile("s_waitcnt lgkmcnt(0)" ::: "memory"); \
    __builtin_amdgcn_sched_barrier(0); \
    __builtin_amdgcn_s_barrier(); \
    if (PREFETCH) STAGE_AB((KT) & 1, ((KT) + 2) * 64); \
    acc[0][0] = MFMA(af0, bf0, acc[0][0]); \
    acc[0][1] = MFMA(af0, bf2, acc[0][1]); \
    acc[1][0] = MFMA(af2, bf0, acc[1][0]); \
    acc[1][1] = MFMA(af2, bf2, acc[1][1]); \
    acc[0][0] = MFMA(af1, bf1, acc[0][0]); \
    acc[0][1] = MFMA(af1, bf3, acc[0][1]); \
    acc[1][0] = MFMA(af3, bf1, acc[1][0]); \
    acc[1][1] = MFMA(af3, bf3, acc[1][1]); \
    if (!(LAST)) { \
      asm volatile("s_waitcnt " VMSTR ::: "memory"); \
      __builtin_amdgcn_sched_barrier(0); \
      __builtin_amdgcn_s_barrier(); \
    } \
  } while (0)

  // ---- prologue: tiles 0 and 1 in flight; wait tile 0; barrier ----
  STAGE_AB(0, 0);
  STAGE_AB(1, 64);
  asm volatile("s_waitcnt vmcnt(4)" ::: "memory");
  __builtin_amdgcn_sched_barrier(0);
  __builtin_amdgcn_s_barrier();

  K_ITER(0, 1, "vmcnt(4)", 0);
  K_ITER(1, 1, "vmcnt(4)", 0);
  K_ITER(2, 1, "vmcnt(4)", 0);
  K_ITER(3, 1, "vmcnt(4)", 0);
  K_ITER(4, 1, "vmcnt(4)", 0);
  K_ITER(5, 1, "vmcnt(4)", 0);
  K_ITER(6, 0, "vmcnt(0)", 0);
  K_ITER(7, 0, "vmcnt(0)", 1);

#undef K_ITER
#undef MFMA
#undef STAGE_AB

  // ---- epilogue: COALESCED store to ws2[p][b][e] (f32, bias applied).
  // Lanes fr=0..15 write 16 consecutive e -> one full 64B line per segment.
  const int q4 = fq * 4;
  #pragma unroll
  for (int jj = 0; jj < 2; ++jj) {
    const int e  = e0t + wc * 32 + jj * 16 + fr;
    const float bv = bias[p * E_ + e];
    #pragma unroll
    for (int ii = 0; ii < 2; ++ii) {
      const int r0 = b0 + wr * 32 + ii * 16 + q4;
      #pragma unroll
      for (int rg = 0; rg < 4; ++rg) {
        ws2[((size_t)p * B_ + (r0 + rg)) * E_ + e] = acc[ii][jj][rg] + bv;
      }
    }
  }
}

// ---------------------------------------------------------------------------
// Pass 3: ws2[p][b][e] -> out[b][e][p], padded-LDS 64x64 f32 transpose,
// coalesced read (e-contiguous) and write (p-contiguous).
// Grid: (b=256, pblk=2, eblk=2).
// ---------------------------------------------------------------------------
__global__ __launch_bounds__(256) void out_transpose_kernel(
    const float* __restrict__ ws2, float* __restrict__ out) {
  __shared__ float tile[64][65];

  const int b  = blockIdx.x;
  const int p0 = blockIdx.y * 64;
  const int e0 = blockIdx.z * 64;
  const int t  = threadIdx.x;

  const float* s = ws2 + ((size_t)p0 * B_ + b) * E_ + e0;   // row stride B_*E_

  {
    const int lr = t >> 4;          // p-local row 0..15
    const int lc = (t & 15) * 4;    // e-local col
    #pragma unroll
    for (int it = 0; it < 4; ++it) {
      const int r = lr + it * 16;
      const float4 v = *reinterpret_cast<const float4*>(s + (size_t)r * (B_ * E_) + lc);
      tile[r][lc + 0] = v.x; tile[r][lc + 1] = v.y;
      tile[r][lc + 2] = v.z; tile[r][lc + 3] = v.w;
    }
  }
  __syncthreads();

  {
    const int c  = t >> 4;          // e-local col 0..15 (+16 per iter)
    const int wd = (t & 15) * 4;    // p-local row chunk
    #pragma unroll
    for (int it = 0; it < 4; ++it) {
      const int cc = c + it * 16;
      float4 v;
      v.x = tile[wd + 0][cc]; v.y = tile[wd + 1][cc];
      v.z = tile[wd + 2][cc]; v.w = tile[wd + 3][cc];
      *reinterpret_cast<float4*>(out + ((size_t)b * E_ + e0 + cc) * P_ + p0 + wd) = v;
    }
  }
}

// ---------------------------------------------------------------------------
// Fallback (only if workspace is too small): naive but correct.
// ---------------------------------------------------------------------------
__global__ __launch_bounds__(256) void naive_kernel(
    const float* __restrict__ x, const float* __restrict__ W,
    const float* __restrict__ bias, float* __restrict__ out) {
  const size_t idx = (size_t)blockIdx.x * 256 + threadIdx.x;
  const int p = (int)(idx & 127);
  const int e = (int)((idx >> 7) & 127);
  const int b = (int)(idx >> 14);
  float acc = bias[p * E_ + e];
  const float* xp = x + (size_t)b * D_ * P_ + p;
  const float* wp = W + (size_t)p * D_ * E_ + e;
  for (int d = 0; d < D_; ++d) acc += xp[(size_t)d * P_] * wp[(size_t)d * E_];
  out[idx] = acc;
}

extern "C" void kernel_launch(void* const* d_in, const int* in_sizes, int n_in,
                              void* d_out, int out_size, void* d_ws, size_t ws_size,
                              hipStream_t stream) {
  (void)in_sizes; (void)n_in; (void)out_size;
  const float* x    = (const float*)d_in[0];   // [B,D,P] f32
  const float* W    = (const float*)d_in[1];   // [P,D,E] f32
  const float* bias = (const float*)d_in[2];   // [P,E]   f32
  float* out = (float*)d_out;                  // [B,E,P] f32

  const size_t xT_bytes  = (size_t)P_ * B_ * D_ * 2;        // 32 MiB
  const size_t Wt_bytes  = (size_t)P_ * E_ * D_ * 2;        // 16 MiB
  const size_t ws2_bytes = (size_t)P_ * B_ * E_ * 4;        // 16 MiB

  if (ws_size < xT_bytes + Wt_bytes + ws2_bytes) {
    naive_kernel<<<dim3((B_ * E_ * P_) / 256), 256, 0, stream>>>(x, W, bias, out);
    return;
  }

  u16*   xT  = (u16*)d_ws;                                  // [P][B][D] bf16
  u16*   Wt  = (u16*)((char*)d_ws + xT_bytes);              // [P][E][D] bf16
  float* ws2 = (float*)((char*)d_ws + xT_bytes + Wt_bytes); // [P][B][E] f32

  transpose_cvt_kernel<<<dim3(B_, 8, 2), 256, 0, stream>>>(
      x, xT, (size_t)B_ * D_, (size_t)D_);
  transpose_cvt_kernel<<<dim3(P_, 8, 2), 256, 0, stream>>>(
      W, Wt, (size_t)D_, (size_t)E_ * D_);

  gemm_kernel<<<dim3(1024), 256, 0, stream>>>(xT, Wt, bias, ws2);

  out_transpose_kernel<<<dim3(B_, 2, 2), 256, 0, stream>>>(ws2, out);
}